// Round 6
// baseline (620.564 us; speedup 1.0000x reference)
//
#include <hip/hip_runtime.h>
#include <hip/hip_cooperative_groups.h>
#include <math.h>

namespace cg = cooperative_groups;

// Problem constants: B=2, S=2048, U=1024, H=16, DK=64
#define B_NUM 2
#define S_LEN 2048
#define U_DIM 1024
#define H_NUM 16
#define DK 64
#define M_TOT (B_NUM * S_LEN)   // 4096

typedef __attribute__((ext_vector_type(8))) short bf8;   // 8 bf16 (MFMA A/B frag)
typedef __attribute__((ext_vector_type(4))) float f4;    // MFMA C/D frag

// float -> bf16 (round to nearest even), raw ushort bits
__device__ __forceinline__ unsigned short f2bf(float f) {
    union { float f; unsigned int u; } x; x.f = f;
    unsigned int r = x.u + 0x7fffu + ((x.u >> 16) & 1u);
    return (unsigned short)(r >> 16);
}

// packed f32x2 -> bf16x2 (hardware cvt)
__device__ __forceinline__ unsigned int pkbf(float a, float b) {
    unsigned int r;
    asm("v_cvt_pk_bf16_f32 %0, %1, %2" : "=v"(r) : "v"(a), "v"(b));
    return r;
}

// async global->LDS, 16 B per lane; LDS dest = wave-uniform base + lane*16
__device__ __forceinline__ void gl2lds16(const void* g, void* l) {
    __builtin_amdgcn_global_load_lds(
        (const __attribute__((address_space(1))) unsigned int*)g,
        (__attribute__((address_space(3))) unsigned int*)l, 16, 0, 0);
}

// ---------------------------------------------------------------------------
// Phase 0: fp32 -> bf16 conversion (device helper; grid-stride).
// (Kept as a pass: R4 showed the GEMM is staging-path-bound, fp32 staging
// doubles staged bytes and cost +34 us. bf16 conversion stays separate.)
// ---------------------------------------------------------------------------
struct CvtArgs {
    const float* src[7];
    unsigned short* dst[7];
    int n[7];
};

__device__ __forceinline__ void convert_core(const CvtArgs& a, int gtid, int gsz)
{
#pragma unroll
    for (int seg = 0; seg < 7; ++seg) {
        const int nv = a.n[seg] >> 3;
        for (int i = gtid; i < nv; i += gsz) {
            const float* s = a.src[seg] + (size_t)i * 8;
            float4 v0 = *(const float4*)s;
            float4 v1 = *(const float4*)(s + 4);
            uint4 o = {pkbf(v0.x, v0.y), pkbf(v0.z, v0.w),
                       pkbf(v1.x, v1.y), pkbf(v1.z, v1.w)};
            *(uint4*)(a.dst[seg] + (size_t)i * 8) = o;
        }
    }
}

// ---------------------------------------------------------------------------
// bf16 MFMA GEMM, GLOBAL_LOAD_LDS staging (R5, verified: qkv ~<40 us).
// C[M,N] = A[M,K] @ W[N,K]^T + bias, *scale. 128x128 tile, BK=32, LDS dbuf.
// Source column segment pre-rotated by rr=(row>>2)&3 so the conflict-free
// frag-read macros stay unchanged. One barrier per K-iter.
// OMODE: 0 = bf16 [M,U]; 1 = f32 [M,U]; 2 = bf16 V-TRANSPOSED
// layout VT[((b*H+h)*64+d)*S + s]  (fuses the old transpose_v kernel).
// ---------------------------------------------------------------------------
struct GemmLds {
    unsigned short As[2][128][32];
    unsigned short Bs[2][128][32];
};

template <int OMODE>
__device__ __forceinline__ void gemm_core(
    GemmLds& S,
    const unsigned short* __restrict__ A, const unsigned short* __restrict__ W,
    const float* __restrict__ bias, void* __restrict__ Cv, float scale,
    int bx, int by)
{
    const int tid = threadIdx.x;
    const int w = tid >> 6, lane = tid & 63;
    const int quad = lane >> 4, cid = lane & 15;
    const int wy = w >> 1, wx = w & 1;
    const int m0 = by * 128, n0 = bx * 128;

    const int l2 = lane >> 2, s4 = lane & 3;
    const int ra = 32 * w + l2;
    const int rr = (ra >> 2) & 3;
    const int cseg = (((s4 + 4) - rr) & 3) * 8;   // bf16-elem source offset
    const unsigned short* gAs = A + (size_t)(m0 + ra) * U_DIM + cseg;
    const unsigned short* gBs = W + (size_t)(n0 + ra) * U_DIM + cseg;

#define STAGE(buf_, k_) do {                                               \
        gl2lds16(gAs + (k_),              &S.As[buf_][32 * w][0]);         \
        gl2lds16(gAs + (k_) + 16 * U_DIM, &S.As[buf_][32 * w + 16][0]);    \
        gl2lds16(gBs + (k_),              &S.Bs[buf_][32 * w][0]);         \
        gl2lds16(gBs + (k_) + 16 * U_DIM, &S.Bs[buf_][32 * w + 16][0]);    \
    } while (0)

    f4 acc[4][4] = {};

    STAGE(0, 0);                 // prologue: tile 0 in flight

#pragma unroll 2
    for (int k0 = 0; k0 < U_DIM; k0 += 32) {
        const int cur = (k0 >> 5) & 1;
        __syncthreads();         // vmcnt(0)+barrier: cur tile visible
        if (k0 + 32 < U_DIM) STAGE(cur ^ 1, k0 + 32);  // in flight over MFMA

        bf8 af[4], bfr[4];
#pragma unroll
        for (int mt = 0; mt < 4; ++mt) {
            int row = wy * 64 + mt * 16 + cid;
            int seg = (quad + (row >> 2)) & 3;
            af[mt] = *(const bf8*)&S.As[cur][row][seg * 8];
        }
#pragma unroll
        for (int nt = 0; nt < 4; ++nt) {
            int row = wx * 64 + nt * 16 + cid;
            int seg = (quad + (row >> 2)) & 3;
            bfr[nt] = *(const bf8*)&S.Bs[cur][row][seg * 8];
        }
#pragma unroll
        for (int mt = 0; mt < 4; ++mt)
#pragma unroll
            for (int nt = 0; nt < 4; ++nt)
                acc[mt][nt] = __builtin_amdgcn_mfma_f32_16x16x32_bf16(
                    af[mt], bfr[nt], acc[mt][nt], 0, 0, 0);
    }
#undef STAGE

#pragma unroll
    for (int nt = 0; nt < 4; ++nt) {
        int col = n0 + wx * 64 + nt * 16 + cid;
        float bv = bias[col];
#pragma unroll
        for (int mt = 0; mt < 4; ++mt) {
            int rowb = m0 + wy * 64 + mt * 16 + quad * 4;
#pragma unroll
            for (int i = 0; i < 4; ++i) {
                float v = (acc[mt][nt][i] + bv) * scale;
                if constexpr (OMODE == 0) {
                    ((unsigned short*)Cv)[(size_t)(rowb + i) * U_DIM + col] = f2bf(v);
                } else if constexpr (OMODE == 1) {
                    ((float*)Cv)[(size_t)(rowb + i) * U_DIM + col] = v;
                } else {
                    int bb = rowb >> 11;
                    int ss = (rowb & (S_LEN - 1)) + i;
                    size_t idx = ((size_t)(bb * H_NUM + (col >> 6)) * DK + (col & 63))
                                 * S_LEN + ss;
                    ((unsigned short*)Cv)[idx] = f2bf(v);
                }
            }
        }
    }
}

struct QkvArgs {
    const unsigned short* A[3];
    const unsigned short* W[3];
    const float* bias[3];
    unsigned short* C[3];
    float scale[3];
};

// ---------------------------------------------------------------------------
// MFMA flash attention core (R3 structure, verified): SWAPPED QK^T +
// IN-REGISTER P REDISTRIBUTION, no-max softmax (exp2; log2e folded into
// Q-GEMM scale), 32 KB LDS.  XCD-grouped remap via linear block id L.
// ---------------------------------------------------------------------------
struct AttnLds {
    unsigned short Ks[128][64];
    unsigned short Vs[64][128];
};

__device__ __forceinline__ void attn_core(
    AttnLds& AL, int L,
    const unsigned short* __restrict__ Q, const unsigned short* __restrict__ K,
    const unsigned short* __restrict__ VT, unsigned short* __restrict__ O)
{
    const int xcd = L & 7;
    const int j   = L >> 3;          // 0..127 within this XCD
    const int gl  = j & 3;           // which of this XCD's 4 (b,h) groups
    const int i   = j >> 2;          // 0..31
    const int hb  = (xcd << 2) | gl; // 0..31
    const int h = hb & 15, b = hb >> 4;
    // balanced qt permutation: every mod-8 stride-8 4-set sums to 62 k-tiles.
    const int px = i & 7, pk = i >> 3;
    const int qt = (pk == 0) ? 31 - px : (pk == 1) ? 16 + px
                 : (pk == 2) ? 15 - px : px;

    const int q0 = qt * 64;
    const int tid = threadIdx.x, w = tid >> 6, lane = tid & 63;
    const int quad = lane >> 4, cid = lane & 15;

#define KFRAG(r, s) (*(const bf8*)&AL.Ks[r][(((s) ^ ((r) & 7)) * 8)])
#define VFRAG(r, s) (*(const bf8*)&AL.Vs[r][(((((s) & 8) | (((s) ^ (r)) & 7))) * 8)])

    // ---- stage Q once via gl2lds16 into the Ks alias (XOR swizzle) ----
    unsigned short (*QsA)[64] = (unsigned short (*)[64])&AL.Ks[0][0];
    const int srow8 = lane >> 3;                 // 0..7
    const int sw = ((lane & 7) ^ srow8) * 8;     // swizzled source col
    {
        const unsigned short* qg =
            Q + ((size_t)b * S_LEN + q0 + w * 16 + srow8) * U_DIM + h * DK + sw;
        gl2lds16(qg, &QsA[w * 16][0]);
        gl2lds16(qg + 8 * U_DIM, &QsA[w * 16 + 8][0]);
    }
    __syncthreads();
    const bf8 qfa = *(const bf8*)&QsA[w * 16 + cid][(((quad) ^ (cid & 7)) * 8)];
    const bf8 qfb = *(const bf8*)&QsA[w * 16 + cid][((((quad + 4)) ^ (cid & 7)) * 8)];

    // ---- staging addressing ----
    const unsigned short* kgl =
        K + ((size_t)b * S_LEN + w * 32 + srow8) * U_DIM + h * DK + (lane & 7) * 8;
    const int vr0 = lane >> 4;
    const int s16 = lane & 15;
    const unsigned short* vgl =
        VT + ((size_t)(b * H_NUM + h) * DK + w * 16 + vr0) * S_LEN + s16 * 8;
    const int spE = (((s16 & 8) | ((s16 ^ vr0) & 7))) * 8;        // c even
    const int spO = (((s16 & 8) | ((s16 ^ (vr0 + 4)) & 7))) * 8;  // c odd
    const int ksw = ((lane & 7) ^ srow8) * 8;                     // K dest seg

    uint4 kr0, kr1, kr2, kr3, vq0, vq1, vq2, vq3;
#define PREFETCH(kt_) do {                                                    \
        const unsigned short* kp_ = kgl + (size_t)(kt_) * 128 * U_DIM;        \
        kr0 = *(const uint4*)(kp_);                                           \
        kr1 = *(const uint4*)(kp_ + (size_t)8 * U_DIM);                       \
        kr2 = *(const uint4*)(kp_ + (size_t)16 * U_DIM);                      \
        kr3 = *(const uint4*)(kp_ + (size_t)24 * U_DIM);                      \
        const unsigned short* vp_ = vgl + (kt_) * 128;                        \
        vq0 = *(const uint4*)(vp_);                                           \
        vq1 = *(const uint4*)(vp_ + (size_t)4 * S_LEN);                       \
        vq2 = *(const uint4*)(vp_ + (size_t)8 * S_LEN);                       \
        vq3 = *(const uint4*)(vp_ + (size_t)12 * S_LEN);                      \
    } while (0)

    f4 o[4] = {};
    float l_p = 0.0f;                 // per-lane partial row sum (q = cid)
    const int qrow = q0 + w * 16 + cid;

    const int nkt = (qt >> 1) + 1;   // 128-key tiles
    PREFETCH(0);

    for (int kt = 0; kt < nkt; ++kt) {
        __syncthreads();            // prev-iter frag reads done; LDS writable
        *(uint4*)&AL.Ks[w * 32 + 0  + srow8][ksw] = kr0;
        *(uint4*)&AL.Ks[w * 32 + 8  + srow8][ksw] = kr1;
        *(uint4*)&AL.Ks[w * 32 + 16 + srow8][ksw] = kr2;
        *(uint4*)&AL.Ks[w * 32 + 24 + srow8][ksw] = kr3;
        *(uint4*)&AL.Vs[w * 16 + 0  + vr0][spE] = vq0;
        *(uint4*)&AL.Vs[w * 16 + 4  + vr0][spO] = vq1;
        *(uint4*)&AL.Vs[w * 16 + 8  + vr0][spE] = vq2;
        *(uint4*)&AL.Vs[w * 16 + 12 + vr0][spO] = vq3;
        __syncthreads();            // tiles visible
        if (kt + 1 < nkt) PREFETCH(kt + 1);   // in flight across compute

        // ---- S^T = K Q^T (swapped operands): lane holds
        //      S[key = 16t + 4*quad + i][q = cid]; exp2-prescaled. ----
        f4 sc[8];
#pragma unroll
        for (int t = 0; t < 8; ++t) {
            int r = t * 16 + cid;
            f4 a = {};
            a = __builtin_amdgcn_mfma_f32_16x16x32_bf16(KFRAG(r, quad), qfa, a, 0, 0, 0);
            a = __builtin_amdgcn_mfma_f32_16x16x32_bf16(KFRAG(r, quad + 4), qfb, a, 0, 0, 0);
            sc[t] = a;
        }

        // ---- causal mask (last tile only) ----
        if (kt == nkt - 1) {
#pragma unroll
            for (int t = 0; t < 8; ++t) {
#pragma unroll
                for (int i2 = 0; i2 < 4; ++i2) {
                    int key = kt * 128 + t * 16 + quad * 4 + i2;
                    if (key > qrow) sc[t][i2] = -1e30f;
                }
            }
        }

        // ---- exp2 + per-lane partial l ----
#pragma unroll
        for (int t = 0; t < 8; ++t) {
#pragma unroll
            for (int i2 = 0; i2 < 4; ++i2) {
                float p = exp2f(sc[t][i2]);
                sc[t][i2] = p;
                l_p += p;
            }
        }

        // ---- pack P pairs, route via permlane32_swap + ds_swizzle ----
        unsigned int r_[8], r2_[8];
#pragma unroll
        for (int t = 0; t < 8; ++t) {
            r_[t]  = pkbf(sc[t][0], sc[t][1]);
            r2_[t] = pkbf(sc[t][2], sc[t][3]);
        }

        const bool qodd = (quad & 1) != 0;
#pragma unroll
        for (int f = 0; f < 4; ++f) {
            unsigned int xa = r_[2 * f], ya = r_[2 * f + 1];
            asm("v_permlane32_swap_b32 %0, %1" : "+v"(xa), "+v"(ya));
            unsigned int xas = __builtin_amdgcn_ds_swizzle((int)xa, 0x401f);
            unsigned int yas = __builtin_amdgcn_ds_swizzle((int)ya, 0x401f);
            unsigned int xb = r2_[2 * f], yb = r2_[2 * f + 1];
            asm("v_permlane32_swap_b32 %0, %1" : "+v"(xb), "+v"(yb));
            unsigned int xbs = __builtin_amdgcn_ds_swizzle((int)xb, 0x401f);
            unsigned int ybs = __builtin_amdgcn_ds_swizzle((int)yb, 0x401f);
            unsigned int u0 = qodd ? yas : xa;
            unsigned int u1 = qodd ? ybs : xb;
            unsigned int u2 = qodd ? ya : xas;
            unsigned int u3 = qodd ? yb : xbs;
            union { uint4 u; bf8 v; } pf;
            pf.u = (uint4){u0, u1, u2, u3};
#pragma unroll
            for (int t = 0; t < 4; ++t) {
                int r = t * 16 + cid;
                o[t] = __builtin_amdgcn_mfma_f32_16x16x32_bf16(
                    pf.v, VFRAG(r, 4 * f + quad), o[t], 0, 0, 0);
            }
        }
    }
#undef PREFETCH
#undef KFRAG
#undef VFRAG

    // ---- epilogue: l reduce across quads, O/l -> bf16 [b,s,u] ----
    float l = l_p;
    l += __shfl_xor(l, 16);
    l += __shfl_xor(l, 32);
    const float inv = 1.0f / l;
#pragma unroll
    for (int i2 = 0; i2 < 4; ++i2) {
        float invi = __shfl(inv, (lane & 48) | (quad * 4 + i2));
        int rowg = q0 + w * 16 + quad * 4 + i2;
        size_t rbase = ((size_t)b * S_LEN + rowg) * U_DIM + h * DK;
#pragma unroll
        for (int t = 0; t < 4; ++t)
            O[rbase + t * 16 + cid] = f2bf(o[t][i2] * invi);
    }
}

// ---------------------------------------------------------------------------
// FUSED COOPERATIVE KERNEL (R6): convert | qkv | attn | obf in one launch,
// grid.sync() between phases. 1024 blocks x 256 thr = 4 blocks/CU exactly
// (32 KB LDS, <=128 VGPR via launch_bounds). Removes 3 inter-kernel
// launch gaps (accounting: kernels sum ~145 us vs dur 225 us).
// Work maps (round-robin block->CU assumed, L = blockIdx.x):
//   qkv: L < 768 (3 jobs/CU) ; attn: all ; obf: L < 256 (1 job/CU).
// ---------------------------------------------------------------------------
struct FusedArgs {
    CvtArgs cvt;
    QkvArgs qkv;
    const unsigned short *Qg, *Kg, *VTg;
    unsigned short* Og;
    const unsigned short* Ao;
    const unsigned short* Wob;
    const float* bo;
    float* outp;
};

__global__ __launch_bounds__(256, 4) void fused_all(FusedArgs a)
{
    __shared__ __align__(16) unsigned char LDSRAW[32768];
    const int L = (int)blockIdx.x;

    // ---- phase 0: fp32 -> bf16 ----
    convert_core(a.cvt, L * 256 + (int)threadIdx.x, (int)gridDim.x * 256);
    cg::this_grid().sync();

    // ---- phase 1: QKV GEMMs (768 jobs) ----
    {
        const int xcd = L & 7, j = L >> 3;       // j in [0,128)
        if (j < 96) {
            GemmLds& S = *(GemmLds*)LDSRAW;
            const int z = j >> 5, r = j & 31;
            const int by = xcd * 4 + (r & 3);
            const int bx = r >> 2;
            if (z == 2)
                gemm_core<2>(S, a.qkv.A[2], a.qkv.W[2], a.qkv.bias[2],
                             a.qkv.C[2], a.qkv.scale[2], bx, by);
            else
                gemm_core<0>(S, a.qkv.A[z], a.qkv.W[z], a.qkv.bias[z],
                             a.qkv.C[z], a.qkv.scale[z], bx, by);
        }
    }
    cg::this_grid().sync();

    // ---- phase 2: attention (1024 jobs) ----
    attn_core(*(AttnLds*)LDSRAW, L, a.Qg, a.Kg, a.VTg, a.Og);
    cg::this_grid().sync();

    // ---- phase 3: output projection (256 jobs, one per CU) ----
    {
        const int xcd = L & 7, j = L >> 3;
        if (j < 32) {
            GemmLds& S = *(GemmLds*)LDSRAW;
            const int by = xcd * 4 + (j & 3);
            const int bx = j >> 2;
            gemm_core<1>(S, a.Ao, a.Wob, a.bo, a.outp, 1.0f, bx, by);
        }
    }
}

// ---------------------------------------------------------------------------
// Fallback standalone kernels (used only if cooperative launch fails).
// ---------------------------------------------------------------------------
__global__ __launch_bounds__(256) void convert_bf16(CvtArgs a) {
    convert_core(a, (int)(blockIdx.x * 256 + threadIdx.x),
                 (int)gridDim.x * 256);
}

__global__ __launch_bounds__(256, 3) void gemm_qkv(QkvArgs a) {
    __shared__ GemmLds S;
    const int L = (int)blockIdx.x + 8 * ((int)blockIdx.y + 32 * (int)blockIdx.z);
    const int xcd = L & 7, j = L >> 3;
    const int z = j >> 5, r = j & 31;
    const int by = xcd * 4 + (r & 3);
    const int bx = r >> 2;
    if (z == 2)
        gemm_core<2>(S, a.A[2], a.W[2], a.bias[2], a.C[2], a.scale[2], bx, by);
    else
        gemm_core<0>(S, a.A[z], a.W[z], a.bias[z], a.C[z], a.scale[z], bx, by);
}

__global__ __launch_bounds__(256, 3) void gemm_obf(
    const unsigned short* __restrict__ A, const unsigned short* __restrict__ W,
    const float* __restrict__ bias, float* __restrict__ C) {
    __shared__ GemmLds S;
    const int L = (int)blockIdx.x + 8 * (int)blockIdx.y;
    const int xcd = L & 7, j = L >> 3;
    const int by = xcd * 4 + (j & 3);
    const int bx = j >> 2;
    gemm_core<1>(S, A, W, bias, C, 1.0f, bx, by);
}

__global__ __launch_bounds__(256, 4) void attn_mfma(
    const unsigned short* __restrict__ Q, const unsigned short* __restrict__ K,
    const unsigned short* __restrict__ VT, unsigned short* __restrict__ O) {
    __shared__ AttnLds AL;
    const int L = (int)blockIdx.x + 32 * ((int)blockIdx.y + 16 * (int)blockIdx.z);
    attn_core(AL, L, Q, K, VT, O);
}

// ---------------------------------------------------------------------------
// ws layout (bf16): xq|xk|xv (8MB ea) | wq|wk|wv|wo (2MB ea) |
//                   qg|kg|vt|ao (8MB ea)  = 64 MB total.
// ---------------------------------------------------------------------------
extern "C" void kernel_launch(void* const* d_in, const int* in_sizes, int n_in,
                              void* d_out, int out_size, void* d_ws, size_t ws_size,
                              hipStream_t stream)
{
    const float* query = (const float*)d_in[0];
    const float* key   = (const float*)d_in[1];
    const float* value = (const float*)d_in[2];
    const float* Wq = (const float*)d_in[4];
    const float* bq = (const float*)d_in[5];
    const float* Wk = (const float*)d_in[6];
    const float* bk = (const float*)d_in[7];
    const float* Wv = (const float*)d_in[8];
    const float* bv = (const float*)d_in[9];
    const float* Wo = (const float*)d_in[10];
    const float* bo = (const float*)d_in[11];
    float* out = (float*)d_out;

    const size_t ACT = (size_t)M_TOT * U_DIM;
    const size_t WT  = (size_t)U_DIM * U_DIM;

    unsigned short* xq  = (unsigned short*)d_ws;
    unsigned short* xk  = xq + ACT;
    unsigned short* xv  = xk + ACT;
    unsigned short* wqb = xv + ACT;
    unsigned short* wkb = wqb + WT;
    unsigned short* wvb = wkb + WT;
    unsigned short* wob = wvb + WT;
    unsigned short* qg  = wob + WT;
    unsigned short* kg  = qg + ACT;
    unsigned short* vt  = kg + ACT;
    unsigned short* ao  = vt + ACT;

    FusedArgs fa;
    fa.cvt.src[0] = query; fa.cvt.dst[0] = xq;  fa.cvt.n[0] = (int)ACT;
    fa.cvt.src[1] = key;   fa.cvt.dst[1] = xk;  fa.cvt.n[1] = (int)ACT;
    fa.cvt.src[2] = value; fa.cvt.dst[2] = xv;  fa.cvt.n[2] = (int)ACT;
    fa.cvt.src[3] = Wq;    fa.cvt.dst[3] = wqb; fa.cvt.n[3] = (int)WT;
    fa.cvt.src[4] = Wk;    fa.cvt.dst[4] = wkb; fa.cvt.n[4] = (int)WT;
    fa.cvt.src[5] = Wv;    fa.cvt.dst[5] = wvb; fa.cvt.n[5] = (int)WT;
    fa.cvt.src[6] = Wo;    fa.cvt.dst[6] = wob; fa.cvt.n[6] = (int)WT;

    // Q scale folds softmax's 1/sqrt(DK) AND log2(e) (attn uses exp2).
    fa.qkv.A[0] = xq; fa.qkv.W[0] = wqb; fa.qkv.bias[0] = bq; fa.qkv.C[0] = qg;
    fa.qkv.scale[0] = 0.125f * 1.44269504088896340736f;
    fa.qkv.A[1] = xk; fa.qkv.W[1] = wkb; fa.qkv.bias[1] = bk; fa.qkv.C[1] = kg;
    fa.qkv.scale[1] = 1.0f;
    fa.qkv.A[2] = xv; fa.qkv.W[2] = wvb; fa.qkv.bias[2] = bv; fa.qkv.C[2] = vt;
    fa.qkv.scale[2] = 1.0f;

    fa.Qg = qg; fa.Kg = kg; fa.VTg = vt; fa.Og = ao;
    fa.Ao = ao; fa.Wob = wob; fa.bo = bo; fa.outp = out;

    void* kargs[] = { (void*)&fa };
    hipError_t e = hipLaunchCooperativeKernel(
        (const void*)fused_all, dim3(1024), dim3(256), kargs, 0, stream);

    if (e != hipSuccess) {
        // Fallback: 4-launch pipeline (R5 behavior).
        convert_bf16<<<dim3(64, 1), 256, 0, stream>>>(fa.cvt);
        gemm_qkv<<<dim3(8, 32, 3), 256, 0, stream>>>(fa.qkv);
        attn_mfma<<<dim3(32, 16, 2), 256, 0, stream>>>(qg, kg, vt, ao);
        gemm_obf<<<dim3(8, 32), 256, 0, stream>>>(ao, wob, bo, out);
    }
}

// Round 7
// 227.168 us; speedup vs baseline: 2.7317x; 2.7317x over previous
//
#include <hip/hip_runtime.h>
#include <math.h>

// Problem constants: B=2, S=2048, U=1024, H=16, DK=64
#define B_NUM 2
#define S_LEN 2048
#define U_DIM 1024
#define H_NUM 16
#define DK 64
#define M_TOT (B_NUM * S_LEN)   // 4096

typedef __attribute__((ext_vector_type(8))) short bf8;   // 8 bf16 (MFMA A/B frag)
typedef __attribute__((ext_vector_type(4))) float f4;    // MFMA C/D frag

// float -> bf16 (round to nearest even), raw ushort bits
__device__ __forceinline__ unsigned short f2bf(float f) {
    union { float f; unsigned int u; } x; x.f = f;
    unsigned int r = x.u + 0x7fffu + ((x.u >> 16) & 1u);
    return (unsigned short)(r >> 16);
}

// packed f32x2 -> bf16x2 (hardware cvt)
__device__ __forceinline__ unsigned int pkbf(float a, float b) {
    unsigned int r;
    asm("v_cvt_pk_bf16_f32 %0, %1, %2" : "=v"(r) : "v"(a), "v"(b));
    return r;
}

// async global->LDS, 16 B per lane; LDS dest = wave-uniform base + lane*16
__device__ __forceinline__ void gl2lds16(const void* g, void* l) {
    __builtin_amdgcn_global_load_lds(
        (const __attribute__((address_space(1))) unsigned int*)g,
        (__attribute__((address_space(3))) unsigned int*)l, 16, 0, 0);
}

// ---------------------------------------------------------------------------
// Bulk fp32 -> bf16 conversion. blockIdx.y selects one of 7 tensors.
// (R4 lesson: GEMM is staging-path-bound; fp32 staging doubles staged
// bytes, +34 us. Conversion stays a separate BW-bound pass, ~roofline.)
// ---------------------------------------------------------------------------
struct CvtArgs {
    const float* src[7];
    unsigned short* dst[7];
    int n[7];
};

__global__ __launch_bounds__(256) void convert_bf16(CvtArgs a)
{
    const int seg = blockIdx.y;
    const int i = (blockIdx.x * 256 + threadIdx.x) * 8;
    if (i >= a.n[seg]) return;
    const float* s = a.src[seg] + i;
    float4 v0 = *(const float4*)s;
    float4 v1 = *(const float4*)(s + 4);
    uint4 o = {pkbf(v0.x, v0.y), pkbf(v0.z, v0.w),
               pkbf(v1.x, v1.y), pkbf(v1.z, v1.w)};
    *(uint4*)(a.dst[seg] + i) = o;
}

// ---------------------------------------------------------------------------
// bf16 MFMA GEMM, R7: GLOBAL_LOAD_LDS staging + TRIPLE-BUFFER LDS +
// COUNTED vmcnt (T4). 2 tiles in flight; s_waitcnt vmcnt(4) per iter
// (each STAGE = 4 gl_lds, so vmcnt(4) = oldest tile done, next still
// flying), vmcnt(0) only on the last tile. STAGE(t+2) is issued AFTER the
// barrier so no wave can still be reading the buffer it overwrites
// (buf[(t+2)%3] == buf[(t-1)%3], whose reads finished before the barrier).
// 48 KB LDS -> still 3 blocks/CU. One raw s_barrier per K-iter.
// C[M,N] = A[M,K] @ W[N,K]^T + bias, *scale. 128x128 tile, BK=32.
// Source column segment pre-rotated by rr=(row>>2)&3 so the conflict-free
// frag-read macros stay unchanged (R5, verified).
// OMODE: 0 = bf16 [M,U]; 1 = f32 [M,U]; 2 = bf16 V-TRANSPOSED
// layout VT[((b*H+h)*64+d)*S + s]  (fuses the old transpose_v kernel).
// ---------------------------------------------------------------------------
struct GemmLds {
    unsigned short As[3][128][32];
    unsigned short Bs[3][128][32];
};

template <int OMODE>
__device__ __forceinline__ void gemm_core(
    GemmLds& S,
    const unsigned short* __restrict__ A, const unsigned short* __restrict__ W,
    const float* __restrict__ bias, void* __restrict__ Cv, float scale,
    int bx, int by)
{
    const int tid = threadIdx.x;
    const int w = tid >> 6, lane = tid & 63;
    const int quad = lane >> 4, cid = lane & 15;
    const int wy = w >> 1, wx = w & 1;
    const int m0 = by * 128, n0 = bx * 128;

    const int l2 = lane >> 2, s4 = lane & 3;
    const int ra = 32 * w + l2;
    const int rr = (ra >> 2) & 3;
    const int cseg = (((s4 + 4) - rr) & 3) * 8;   // bf16-elem source offset
    const unsigned short* gAs = A + (size_t)(m0 + ra) * U_DIM + cseg;
    const unsigned short* gBs = W + (size_t)(n0 + ra) * U_DIM + cseg;

#define STAGE(buf_, k_) do {                                               \
        gl2lds16(gAs + (k_),              &S.As[buf_][32 * w][0]);         \
        gl2lds16(gAs + (k_) + 16 * U_DIM, &S.As[buf_][32 * w + 16][0]);    \
        gl2lds16(gBs + (k_),              &S.Bs[buf_][32 * w][0]);         \
        gl2lds16(gBs + (k_) + 16 * U_DIM, &S.Bs[buf_][32 * w + 16][0]);    \
    } while (0)

    f4 acc[4][4] = {};

    // prologue: tiles 0 and 1 in flight (8 outstanding gl_lds per wave)
    STAGE(0, 0);
    STAGE(1, 32);

    int cur = 0;
    for (int k0 = 0; k0 < U_DIM; k0 += 32) {
        // steady state: outstanding = {tile t (oldest 4), tile t+1 (4)}.
        // vmcnt(4) -> tile t's writes (this wave) complete; barrier makes
        // every wave's tile-t writes visible and proves all waves finished
        // reading buf[(t-1)%3] (overwritten by STAGE below).
        if (k0 == U_DIM - 32) asm volatile("s_waitcnt vmcnt(0)" ::: "memory");
        else                  asm volatile("s_waitcnt vmcnt(4)" ::: "memory");
        __builtin_amdgcn_s_barrier();
        __builtin_amdgcn_sched_barrier(0);

        int nxt2 = cur + 2; if (nxt2 >= 3) nxt2 -= 3;
        if (k0 + 64 < U_DIM) STAGE(nxt2, k0 + 64);   // 2-deep, in flight

        bf8 af[4], bfr[4];
#pragma unroll
        for (int mt = 0; mt < 4; ++mt) {
            int row = wy * 64 + mt * 16 + cid;
            int seg = (quad + (row >> 2)) & 3;
            af[mt] = *(const bf8*)&S.As[cur][row][seg * 8];
        }
#pragma unroll
        for (int nt = 0; nt < 4; ++nt) {
            int row = wx * 64 + nt * 16 + cid;
            int seg = (quad + (row >> 2)) & 3;
            bfr[nt] = *(const bf8*)&S.Bs[cur][row][seg * 8];
        }
#pragma unroll
        for (int mt = 0; mt < 4; ++mt)
#pragma unroll
            for (int nt = 0; nt < 4; ++nt)
                acc[mt][nt] = __builtin_amdgcn_mfma_f32_16x16x32_bf16(
                    af[mt], bfr[nt], acc[mt][nt], 0, 0, 0);

        cur = (cur == 2) ? 0 : cur + 1;
    }
#undef STAGE

#pragma unroll
    for (int nt = 0; nt < 4; ++nt) {
        int col = n0 + wx * 64 + nt * 16 + cid;
        float bv = bias[col];
#pragma unroll
        for (int mt = 0; mt < 4; ++mt) {
            int rowb = m0 + wy * 64 + mt * 16 + quad * 4;
#pragma unroll
            for (int i = 0; i < 4; ++i) {
                float v = (acc[mt][nt][i] + bv) * scale;
                if constexpr (OMODE == 0) {
                    ((unsigned short*)Cv)[(size_t)(rowb + i) * U_DIM + col] = f2bf(v);
                } else if constexpr (OMODE == 1) {
                    ((float*)Cv)[(size_t)(rowb + i) * U_DIM + col] = v;
                } else {
                    // V output written directly in transposed layout:
                    // [b, s, h*64+d] -> VT[((b*H+h)*64+d)*S + s]
                    int bb = rowb >> 11;
                    int ss = (rowb & (S_LEN - 1)) + i;
                    size_t idx = ((size_t)(bb * H_NUM + (col >> 6)) * DK + (col & 63))
                                 * S_LEN + ss;
                    ((unsigned short*)Cv)[idx] = f2bf(v);
                }
            }
        }
    }
}

struct QkvArgs {
    const unsigned short* A[3];
    const unsigned short* W[3];
    const float* bias[3];
    unsigned short* C[3];
    float scale[3];
};

// XCD remap (R2, verified): each XCD owns 4 m-tiles x 8 n-tiles per z-slice.
__global__ __launch_bounds__(256, 3) void gemm_qkv(QkvArgs a) {
    __shared__ GemmLds S;
    const int L = (int)blockIdx.x + 8 * ((int)blockIdx.y + 32 * (int)blockIdx.z);
    const int xcd = L & 7, j = L >> 3;       // j in [0,96)
    const int z = j >> 5, r = j & 31;        // r in [0,32)
    const int by = xcd * 4 + (r & 3);
    const int bx = r >> 2;
    if (z == 2)
        gemm_core<2>(S, a.A[2], a.W[2], a.bias[2], a.C[2], a.scale[2], bx, by);
    else
        gemm_core<0>(S, a.A[z], a.W[z], a.bias[z], a.C[z], a.scale[z], bx, by);
}

__global__ __launch_bounds__(256, 3) void gemm_obf(
    const unsigned short* __restrict__ A, const unsigned short* __restrict__ W,
    const float* __restrict__ bias, float* __restrict__ C) {
    __shared__ GemmLds S;
    const int L = (int)blockIdx.x + 8 * (int)blockIdx.y;
    const int xcd = L & 7, j = L >> 3;       // j in [0,32)
    const int by = xcd * 4 + (j & 3);
    const int bx = j >> 2;
    gemm_core<1>(S, A, W, bias, C, 1.0f, bx, by);
}

// ---------------------------------------------------------------------------
// MFMA flash attention (R3 structure, verified): SWAPPED QK^T + IN-REGISTER
// P REDISTRIBUTION (cvt_pk + permlane32_swap + ds_swizzle), no-max softmax
// (exp2; log2e folded into Q-GEMM scale), 32 KB LDS -> 4 blocks/CU, whole
// 1024-block grid resident.  XCD-grouped remap (R2: FETCH 63->12 MB).
// ---------------------------------------------------------------------------
__global__ __launch_bounds__(256, 4) void attn_mfma(
    const unsigned short* __restrict__ Q, const unsigned short* __restrict__ K,
    const unsigned short* __restrict__ VT, unsigned short* __restrict__ O)
{
    __shared__ __align__(16) unsigned short Ks[128][64];   // also Q staging alias
    __shared__ __align__(16) unsigned short Vs[64][128];

    // ---- XCD-grouping remap (linear-ID % 8 = XCD round-robin) ----
    const int L = (int)blockIdx.x + 32 * ((int)blockIdx.y + 16 * (int)blockIdx.z);
    const int xcd = L & 7;
    const int j   = L >> 3;          // 0..127 within this XCD
    const int gl  = j & 3;           // which of this XCD's 4 (b,h) groups
    const int i   = j >> 2;          // 0..31
    const int hb  = (xcd << 2) | gl; // 0..31
    const int h = hb & 15, b = hb >> 4;
    // balanced qt permutation: every mod-8 stride-8 4-set sums to 62 k-tiles.
    const int px = i & 7, pk = i >> 3;
    const int qt = (pk == 0) ? 31 - px : (pk == 1) ? 16 + px
                 : (pk == 2) ? 15 - px : px;

    const int q0 = qt * 64;
    const int tid = threadIdx.x, w = tid >> 6, lane = tid & 63;
    const int quad = lane >> 4, cid = lane & 15;

#define KFRAG(r, s) (*(const bf8*)&Ks[r][(((s) ^ ((r) & 7)) * 8)])
#define VFRAG(r, s) (*(const bf8*)&Vs[r][(((((s) & 8) | (((s) ^ (r)) & 7))) * 8)])

    // ---- stage Q once via gl2lds16 into the Ks alias (XOR swizzle) ----
    unsigned short (*QsA)[64] = (unsigned short (*)[64])&Ks[0][0];
    const int srow8 = lane >> 3;                 // 0..7
    const int sw = ((lane & 7) ^ srow8) * 8;     // swizzled source col
    {
        const unsigned short* qg =
            Q + ((size_t)b * S_LEN + q0 + w * 16 + srow8) * U_DIM + h * DK + sw;
        gl2lds16(qg, &QsA[w * 16][0]);
        gl2lds16(qg + 8 * U_DIM, &QsA[w * 16 + 8][0]);
    }
    __syncthreads();
    const bf8 qfa = *(const bf8*)&QsA[w * 16 + cid][(((quad) ^ (cid & 7)) * 8)];
    const bf8 qfb = *(const bf8*)&QsA[w * 16 + cid][((((quad + 4)) ^ (cid & 7)) * 8)];

    // ---- staging addressing ----
    const unsigned short* kgl =
        K + ((size_t)b * S_LEN + w * 32 + srow8) * U_DIM + h * DK + (lane & 7) * 8;
    const int vr0 = lane >> 4;
    const int s16 = lane & 15;
    const unsigned short* vgl =
        VT + ((size_t)(b * H_NUM + h) * DK + w * 16 + vr0) * S_LEN + s16 * 8;
    const int spE = (((s16 & 8) | ((s16 ^ vr0) & 7))) * 8;        // c even
    const int spO = (((s16 & 8) | ((s16 ^ (vr0 + 4)) & 7))) * 8;  // c odd
    const int ksw = ((lane & 7) ^ srow8) * 8;                     // K dest seg

    uint4 kr0, kr1, kr2, kr3, vq0, vq1, vq2, vq3;
#define PREFETCH(kt_) do {                                                    \
        const unsigned short* kp_ = kgl + (size_t)(kt_) * 128 * U_DIM;        \
        kr0 = *(const uint4*)(kp_);                                           \
        kr1 = *(const uint4*)(kp_ + (size_t)8 * U_DIM);                       \
        kr2 = *(const uint4*)(kp_ + (size_t)16 * U_DIM);                      \
        kr3 = *(const uint4*)(kp_ + (size_t)24 * U_DIM);                      \
        const unsigned short* vp_ = vgl + (kt_) * 128;                        \
        vq0 = *(const uint4*)(vp_);                                           \
        vq1 = *(const uint4*)(vp_ + (size_t)4 * S_LEN);                       \
        vq2 = *(const uint4*)(vp_ + (size_t)8 * S_LEN);                       \
        vq3 = *(const uint4*)(vp_ + (size_t)12 * S_LEN);                      \
    } while (0)

    f4 o[4] = {};
    float l_p = 0.0f;                 // per-lane partial row sum (q = cid)
    const int qrow = q0 + w * 16 + cid;

    const int nkt = (qt >> 1) + 1;   // 128-key tiles
    PREFETCH(0);

    for (int kt = 0; kt < nkt; ++kt) {
        __syncthreads();            // prev-iter frag reads done; LDS writable
        *(uint4*)&Ks[w * 32 + 0  + srow8][ksw] = kr0;
        *(uint4*)&Ks[w * 32 + 8  + srow8][ksw] = kr1;
        *(uint4*)&Ks[w * 32 + 16 + srow8][ksw] = kr2;
        *(uint4*)&Ks[w * 32 + 24 + srow8][ksw] = kr3;
        *(uint4*)&Vs[w * 16 + 0  + vr0][spE] = vq0;
        *(uint4*)&Vs[w * 16 + 4  + vr0][spO] = vq1;
        *(uint4*)&Vs[w * 16 + 8  + vr0][spE] = vq2;
        *(uint4*)&Vs[w * 16 + 12 + vr0][spO] = vq3;
        __syncthreads();            // tiles visible
        if (kt + 1 < nkt) PREFETCH(kt + 1);   // in flight across compute

        // ---- S^T = K Q^T (swapped operands): lane holds
        //      S[key = 16t + 4*quad + i][q = cid]; exp2-prescaled. ----
        f4 sc[8];
#pragma unroll
        for (int t = 0; t < 8; ++t) {
            int r = t * 16 + cid;
            f4 a = {};
            a = __builtin_amdgcn_mfma_f32_16x16x32_bf16(KFRAG(r, quad), qfa, a, 0, 0, 0);
            a = __builtin_amdgcn_mfma_f32_16x16x32_bf16(KFRAG(r, quad + 4), qfb, a, 0, 0, 0);
            sc[t] = a;
        }

        // ---- causal mask (last tile only) ----
        if (kt == nkt - 1) {
#pragma unroll
            for (int t = 0; t < 8; ++t) {
#pragma unroll
                for (int i2 = 0; i2 < 4; ++i2) {
                    int key = kt * 128 + t * 16 + quad * 4 + i2;
                    if (key > qrow) sc[t][i2] = -1e30f;
                }
            }
        }

        // ---- exp2 + per-lane partial l ----
#pragma unroll
        for (int t = 0; t < 8; ++t) {
#pragma unroll
            for (int i2 = 0; i2 < 4; ++i2) {
                float p = exp2f(sc[t][i2]);
                sc[t][i2] = p;
                l_p += p;
            }
        }

        // ---- pack P pairs, route via permlane32_swap + ds_swizzle ----
        unsigned int r_[8], r2_[8];
#pragma unroll
        for (int t = 0; t < 8; ++t) {
            r_[t]  = pkbf(sc[t][0], sc[t][1]);
            r2_[t] = pkbf(sc[t][2], sc[t][3]);
        }

        const bool qodd = (quad & 1) != 0;
#pragma unroll
        for (int f = 0; f < 4; ++f) {
            unsigned int xa = r_[2 * f], ya = r_[2 * f + 1];
            asm("v_permlane32_swap_b32 %0, %1" : "+v"(xa), "+v"(ya));
            unsigned int xas = __builtin_amdgcn_ds_swizzle((int)xa, 0x401f);
            unsigned int yas = __builtin_amdgcn_ds_swizzle((int)ya, 0x401f);
            unsigned int xb = r2_[2 * f], yb = r2_[2 * f + 1];
            asm("v_permlane32_swap_b32 %0, %1" : "+v"(xb), "+v"(yb));
            unsigned int xbs = __builtin_amdgcn_ds_swizzle((int)xb, 0x401f);
            unsigned int ybs = __builtin_amdgcn_ds_swizzle((int)yb, 0x401f);
            unsigned int u0 = qodd ? yas : xa;
            unsigned int u1 = qodd ? ybs : xb;
            unsigned int u2 = qodd ? ya : xas;
            unsigned int u3 = qodd ? yb : xbs;
            union { uint4 u; bf8 v; } pf;
            pf.u = (uint4){u0, u1, u2, u3};
#pragma unroll
            for (int t = 0; t < 4; ++t) {
                int r = t * 16 + cid;
                o[t] = __builtin_amdgcn_mfma_f32_16x16x32_bf16(
                    pf.v, VFRAG(r, 4 * f + quad), o[t], 0, 0, 0);
            }
        }
    }
#undef PREFETCH
#undef KFRAG
#undef VFRAG

    // ---- epilogue: l reduce across quads, O/l -> bf16 [b,s,u] ----
    float l = l_p;
    l += __shfl_xor(l, 16);
    l += __shfl_xor(l, 32);
    const float inv = 1.0f / l;
#pragma unroll
    for (int i2 = 0; i2 < 4; ++i2) {
        float invi = __shfl(inv, (lane & 48) | (quad * 4 + i2));
        int rowg = q0 + w * 16 + quad * 4 + i2;
        size_t rbase = ((size_t)b * S_LEN + rowg) * U_DIM + h * DK;
#pragma unroll
        for (int t = 0; t < 4; ++t)
            O[rbase + t * 16 + cid] = f2bf(o[t][i2] * invi);
    }
}

// ---------------------------------------------------------------------------
// ws layout (bf16): xq|xk|xv (8MB ea) | wq|wk|wv|wo (2MB ea) |
//                   qg|kg|vt|ao (8MB ea)  = 64 MB total.
// ---------------------------------------------------------------------------
extern "C" void kernel_launch(void* const* d_in, const int* in_sizes, int n_in,
                              void* d_out, int out_size, void* d_ws, size_t ws_size,
                              hipStream_t stream)
{
    const float* query = (const float*)d_in[0];
    const float* key   = (const float*)d_in[1];
    const float* value = (const float*)d_in[2];
    const float* Wq = (const float*)d_in[4];
    const float* bq = (const float*)d_in[5];
    const float* Wk = (const float*)d_in[6];
    const float* bk = (const float*)d_in[7];
    const float* Wv = (const float*)d_in[8];
    const float* bv = (const float*)d_in[9];
    const float* Wo = (const float*)d_in[10];
    const float* bo = (const float*)d_in[11];
    float* out = (float*)d_out;

    const size_t ACT = (size_t)M_TOT * U_DIM;
    const size_t WT  = (size_t)U_DIM * U_DIM;

    unsigned short* xq  = (unsigned short*)d_ws;
    unsigned short* xk  = xq + ACT;
    unsigned short* xv  = xk + ACT;
    unsigned short* wqb = xv + ACT;
    unsigned short* wkb = wqb + WT;
    unsigned short* wvb = wkb + WT;
    unsigned short* wob = wvb + WT;
    unsigned short* qg  = wob + WT;
    unsigned short* kg  = qg + ACT;
    unsigned short* vt  = kg + ACT;
    unsigned short* ao  = vt + ACT;

    CvtArgs ca;
    ca.src[0] = query; ca.dst[0] = xq;  ca.n[0] = (int)ACT;
    ca.src[1] = key;   ca.dst[1] = xk;  ca.n[1] = (int)ACT;
    ca.src[2] = value; ca.dst[2] = xv;  ca.n[2] = (int)ACT;
    ca.src[3] = Wq;    ca.dst[3] = wqb; ca.n[3] = (int)WT;
    ca.src[4] = Wk;    ca.dst[4] = wkb; ca.n[4] = (int)WT;
    ca.src[5] = Wv;    ca.dst[5] = wvb; ca.n[5] = (int)WT;
    ca.src[6] = Wo;    ca.dst[6] = wob; ca.n[6] = (int)WT;
    convert_bf16<<<dim3(ACT / (256 * 8), 7), 256, 0, stream>>>(ca);

    // Q scale folds softmax's 1/sqrt(DK) AND log2(e) (attn uses exp2).
    QkvArgs ga;
    ga.A[0] = xq; ga.W[0] = wqb; ga.bias[0] = bq; ga.C[0] = qg;
    ga.scale[0] = 0.125f * 1.44269504088896340736f;
    ga.A[1] = xk; ga.W[1] = wkb; ga.bias[1] = bk; ga.C[1] = kg; ga.scale[1] = 1.0f;
    ga.A[2] = xv; ga.W[2] = wvb; ga.bias[2] = bv; ga.C[2] = vt; ga.scale[2] = 1.0f;
    gemm_qkv<<<dim3(U_DIM / 128, M_TOT / 128, 3), 256, 0, stream>>>(ga);

    attn_mfma<<<dim3(S_LEN / 64, H_NUM, B_NUM), 256, 0, stream>>>(qg, kg, vt, ao);

    gemm_obf<<<dim3(U_DIM / 128, M_TOT / 128), 256, 0, stream>>>(ao, wob, bo, out);
}

// Round 8
// 220.584 us; speedup vs baseline: 2.8133x; 1.0298x over previous
//
#include <hip/hip_runtime.h>
#include <math.h>

// Problem constants: B=2, S=2048, U=1024, H=16, DK=64
#define B_NUM 2
#define S_LEN 2048
#define U_DIM 1024
#define H_NUM 16
#define DK 64
#define M_TOT (B_NUM * S_LEN)   // 4096

typedef __attribute__((ext_vector_type(8))) short bf8;   // 8 bf16 (MFMA A/B frag)
typedef __attribute__((ext_vector_type(4))) float f4;    // MFMA C/D frag

// float -> bf16 (round to nearest even), raw ushort bits
__device__ __forceinline__ unsigned short f2bf(float f) {
    union { float f; unsigned int u; } x; x.f = f;
    unsigned int r = x.u + 0x7fffu + ((x.u >> 16) & 1u);
    return (unsigned short)(r >> 16);
}

// packed f32x2 -> bf16x2 (hardware cvt)
__device__ __forceinline__ unsigned int pkbf(float a, float b) {
    unsigned int r;
    asm("v_cvt_pk_bf16_f32 %0, %1, %2" : "=v"(r) : "v"(a), "v"(b));
    return r;
}

// async global->LDS, 16 B per lane; LDS dest = wave-uniform base + lane*16
__device__ __forceinline__ void gl2lds16(const void* g, void* l) {
    __builtin_amdgcn_global_load_lds(
        (const __attribute__((address_space(1))) unsigned int*)g,
        (__attribute__((address_space(3))) unsigned int*)l, 16, 0, 0);
}

// ---------------------------------------------------------------------------
// Bulk fp32 -> bf16 conversion. blockIdx.y selects one of 7 tensors.
// (R4 lesson: GEMM is staging-path-bound; fp32 staging doubles staged
// bytes, +34 us. Conversion stays a separate BW-bound pass, ~roofline.)
// ---------------------------------------------------------------------------
struct CvtArgs {
    const float* src[7];
    unsigned short* dst[7];
    int n[7];
};

__global__ __launch_bounds__(256) void convert_bf16(CvtArgs a)
{
    const int seg = blockIdx.y;
    const int i = (blockIdx.x * 256 + threadIdx.x) * 8;
    if (i >= a.n[seg]) return;
    const float* s = a.src[seg] + i;
    float4 v0 = *(const float4*)s;
    float4 v1 = *(const float4*)(s + 4);
    uint4 o = {pkbf(v0.x, v0.y), pkbf(v0.z, v0.w),
               pkbf(v1.x, v1.y), pkbf(v1.z, v1.w)};
    *(uint4*)(a.dst[seg] + i) = o;
}

// ---------------------------------------------------------------------------
// bf16 MFMA GEMM, R5 structure RESTORED (verified best: qkv < 40 us):
// GLOBAL_LOAD_LDS staging, 2-buffer LDS, one __syncthreads per K-iter.
// (R7's triple-buffer + counted vmcnt was neutral on qkv and perturbed the
// co-compiled attn kernel's regalloc (80 -> 52 VGPR, +2.5 us) -- reverted.)
// C[M,N] = A[M,K] @ W[N,K]^T + bias, *scale. 128x128 tile, BK=32.
// Source column segment pre-rotated by rr=(row>>2)&3 so the conflict-free
// frag-read macros stay unchanged.
// OMODE: 0 = bf16 [M,U]; 1 = f32 [M,U]; 2 = bf16 V-TRANSPOSED
// layout VT[((b*H+h)*64+d)*S + s]  (fuses the old transpose_v kernel).
// ---------------------------------------------------------------------------
struct GemmLds {
    unsigned short As[2][128][32];
    unsigned short Bs[2][128][32];
};

template <int OMODE>
__device__ __forceinline__ void gemm_core(
    GemmLds& S,
    const unsigned short* __restrict__ A, const unsigned short* __restrict__ W,
    const float* __restrict__ bias, void* __restrict__ Cv, float scale,
    int bx, int by)
{
    const int tid = threadIdx.x;
    const int w = tid >> 6, lane = tid & 63;
    const int quad = lane >> 4, cid = lane & 15;
    const int wy = w >> 1, wx = w & 1;
    const int m0 = by * 128, n0 = bx * 128;

    const int l2 = lane >> 2, s4 = lane & 3;
    const int ra = 32 * w + l2;
    const int rr = (ra >> 2) & 3;
    const int cseg = (((s4 + 4) - rr) & 3) * 8;   // bf16-elem source offset
    const unsigned short* gAs = A + (size_t)(m0 + ra) * U_DIM + cseg;
    const unsigned short* gBs = W + (size_t)(n0 + ra) * U_DIM + cseg;

#define STAGE(buf_, k_) do {                                               \
        gl2lds16(gAs + (k_),              &S.As[buf_][32 * w][0]);         \
        gl2lds16(gAs + (k_) + 16 * U_DIM, &S.As[buf_][32 * w + 16][0]);    \
        gl2lds16(gBs + (k_),              &S.Bs[buf_][32 * w][0]);         \
        gl2lds16(gBs + (k_) + 16 * U_DIM, &S.Bs[buf_][32 * w + 16][0]);    \
    } while (0)

    f4 acc[4][4] = {};

    STAGE(0, 0);                 // prologue: tile 0 in flight

#pragma unroll 2
    for (int k0 = 0; k0 < U_DIM; k0 += 32) {
        const int cur = (k0 >> 5) & 1;
        __syncthreads();         // vmcnt(0)+barrier: cur tile visible
        if (k0 + 32 < U_DIM) STAGE(cur ^ 1, k0 + 32);  // in flight over MFMA

        bf8 af[4], bfr[4];
#pragma unroll
        for (int mt = 0; mt < 4; ++mt) {
            int row = wy * 64 + mt * 16 + cid;
            int seg = (quad + (row >> 2)) & 3;
            af[mt] = *(const bf8*)&S.As[cur][row][seg * 8];
        }
#pragma unroll
        for (int nt = 0; nt < 4; ++nt) {
            int row = wx * 64 + nt * 16 + cid;
            int seg = (quad + (row >> 2)) & 3;
            bfr[nt] = *(const bf8*)&S.Bs[cur][row][seg * 8];
        }
#pragma unroll
        for (int mt = 0; mt < 4; ++mt)
#pragma unroll
            for (int nt = 0; nt < 4; ++nt)
                acc[mt][nt] = __builtin_amdgcn_mfma_f32_16x16x32_bf16(
                    af[mt], bfr[nt], acc[mt][nt], 0, 0, 0);
    }
#undef STAGE

#pragma unroll
    for (int nt = 0; nt < 4; ++nt) {
        int col = n0 + wx * 64 + nt * 16 + cid;
        float bv = bias[col];
#pragma unroll
        for (int mt = 0; mt < 4; ++mt) {
            int rowb = m0 + wy * 64 + mt * 16 + quad * 4;
#pragma unroll
            for (int i = 0; i < 4; ++i) {
                float v = (acc[mt][nt][i] + bv) * scale;
                if constexpr (OMODE == 0) {
                    ((unsigned short*)Cv)[(size_t)(rowb + i) * U_DIM + col] = f2bf(v);
                } else if constexpr (OMODE == 1) {
                    ((float*)Cv)[(size_t)(rowb + i) * U_DIM + col] = v;
                } else {
                    // V output written directly in transposed layout:
                    // [b, s, h*64+d] -> VT[((b*H+h)*64+d)*S + s]
                    int bb = rowb >> 11;
                    int ss = (rowb & (S_LEN - 1)) + i;
                    size_t idx = ((size_t)(bb * H_NUM + (col >> 6)) * DK + (col & 63))
                                 * S_LEN + ss;
                    ((unsigned short*)Cv)[idx] = f2bf(v);
                }
            }
        }
    }
}

struct QkvArgs {
    const unsigned short* A[3];
    const unsigned short* W[3];
    const float* bias[3];
    unsigned short* C[3];
    float scale[3];
};

// XCD remap (R2, verified): each XCD owns 4 m-tiles x 8 n-tiles per z-slice.
__global__ __launch_bounds__(256, 3) void gemm_qkv(QkvArgs a) {
    __shared__ GemmLds S;
    const int L = (int)blockIdx.x + 8 * ((int)blockIdx.y + 32 * (int)blockIdx.z);
    const int xcd = L & 7, j = L >> 3;       // j in [0,96)
    const int z = j >> 5, r = j & 31;        // r in [0,32)
    const int by = xcd * 4 + (r & 3);
    const int bx = r >> 2;
    if (z == 2)
        gemm_core<2>(S, a.A[2], a.W[2], a.bias[2], a.C[2], a.scale[2], bx, by);
    else
        gemm_core<0>(S, a.A[z], a.W[z], a.bias[z], a.C[z], a.scale[z], bx, by);
}

__global__ __launch_bounds__(256, 3) void gemm_obf(
    const unsigned short* __restrict__ A, const unsigned short* __restrict__ W,
    const float* __restrict__ bias, float* __restrict__ C) {
    __shared__ GemmLds S;
    const int L = (int)blockIdx.x + 8 * (int)blockIdx.y;
    const int xcd = L & 7, j = L >> 3;       // j in [0,32)
    const int by = xcd * 4 + (j & 3);
    const int bx = j >> 2;
    gemm_core<1>(S, A, W, bias, C, 1.0f, bx, by);
}

// ---------------------------------------------------------------------------
// MFMA flash attention, R8: R3 structure + L-VIA-ONES-MFMA.
// Profile showed VALU is the binding pipe (VALUBusy ~50%, MfmaUtil ~17%);
// the 32 l-accumulation v_adds per K-tile are moved to the MFMA pipe:
// o4 = mfma(P_frag, ones, o4) sums P over keys, and lands l for row
// q = 4*quad+i in o4[i] -- exactly the row this lane writes -- so the
// epilogue's 7-shuffle cross-lane l reduction is deleted too.
// Denominator now sums the SAME bf16-rounded P as the numerator.
// ---------------------------------------------------------------------------
__global__ __launch_bounds__(256, 4) void attn_mfma(
    const unsigned short* __restrict__ Q, const unsigned short* __restrict__ K,
    const unsigned short* __restrict__ VT, unsigned short* __restrict__ O)
{
    __shared__ __align__(16) unsigned short Ks[128][64];   // also Q staging alias
    __shared__ __align__(16) unsigned short Vs[64][128];

    // ---- XCD-grouping remap (linear-ID % 8 = XCD round-robin) ----
    const int L = (int)blockIdx.x + 32 * ((int)blockIdx.y + 16 * (int)blockIdx.z);
    const int xcd = L & 7;
    const int j   = L >> 3;          // 0..127 within this XCD
    const int gl  = j & 3;           // which of this XCD's 4 (b,h) groups
    const int i   = j >> 2;          // 0..31
    const int hb  = (xcd << 2) | gl; // 0..31
    const int h = hb & 15, b = hb >> 4;
    // balanced qt permutation: every mod-8 stride-8 4-set sums to 62 k-tiles.
    const int px = i & 7, pk = i >> 3;
    const int qt = (pk == 0) ? 31 - px : (pk == 1) ? 16 + px
                 : (pk == 2) ? 15 - px : px;

    const int q0 = qt * 64;
    const int tid = threadIdx.x, w = tid >> 6, lane = tid & 63;
    const int quad = lane >> 4, cid = lane & 15;

#define KFRAG(r, s) (*(const bf8*)&Ks[r][(((s) ^ ((r) & 7)) * 8)])
#define VFRAG(r, s) (*(const bf8*)&Vs[r][(((((s) & 8) | (((s) ^ (r)) & 7))) * 8)])

    // ---- stage Q once via gl2lds16 into the Ks alias (XOR swizzle) ----
    unsigned short (*QsA)[64] = (unsigned short (*)[64])&Ks[0][0];
    const int srow8 = lane >> 3;                 // 0..7
    const int sw = ((lane & 7) ^ srow8) * 8;     // swizzled source col
    {
        const unsigned short* qg =
            Q + ((size_t)b * S_LEN + q0 + w * 16 + srow8) * U_DIM + h * DK + sw;
        gl2lds16(qg, &QsA[w * 16][0]);
        gl2lds16(qg + 8 * U_DIM, &QsA[w * 16 + 8][0]);
    }
    __syncthreads();
    const bf8 qfa = *(const bf8*)&QsA[w * 16 + cid][(((quad) ^ (cid & 7)) * 8)];
    const bf8 qfb = *(const bf8*)&QsA[w * 16 + cid][((((quad + 4)) ^ (cid & 7)) * 8)];

    // ---- staging addressing ----
    const unsigned short* kgl =
        K + ((size_t)b * S_LEN + w * 32 + srow8) * U_DIM + h * DK + (lane & 7) * 8;
    const int vr0 = lane >> 4;
    const int s16 = lane & 15;
    const unsigned short* vgl =
        VT + ((size_t)(b * H_NUM + h) * DK + w * 16 + vr0) * S_LEN + s16 * 8;
    const int spE = (((s16 & 8) | ((s16 ^ vr0) & 7))) * 8;        // c even
    const int spO = (((s16 & 8) | ((s16 ^ (vr0 + 4)) & 7))) * 8;  // c odd
    const int ksw = ((lane & 7) ^ srow8) * 8;                     // K dest seg

    uint4 kr0, kr1, kr2, kr3, vq0, vq1, vq2, vq3;
#define PREFETCH(kt_) do {                                                    \
        const unsigned short* kp_ = kgl + (size_t)(kt_) * 128 * U_DIM;        \
        kr0 = *(const uint4*)(kp_);                                           \
        kr1 = *(const uint4*)(kp_ + (size_t)8 * U_DIM);                       \
        kr2 = *(const uint4*)(kp_ + (size_t)16 * U_DIM);                      \
        kr3 = *(const uint4*)(kp_ + (size_t)24 * U_DIM);                      \
        const unsigned short* vp_ = vgl + (kt_) * 128;                        \
        vq0 = *(const uint4*)(vp_);                                           \
        vq1 = *(const uint4*)(vp_ + (size_t)4 * S_LEN);                       \
        vq2 = *(const uint4*)(vp_ + (size_t)8 * S_LEN);                       \
        vq3 = *(const uint4*)(vp_ + (size_t)12 * S_LEN);                      \
    } while (0)

    f4 o[4] = {};
    f4 o4 = {};                       // l accumulator: o4[i] = l(q = 4*quad+i)
    union { uint4 u; bf8 v; } onesf;
    onesf.u = (uint4){0x3f803f80u, 0x3f803f80u, 0x3f803f80u, 0x3f803f80u};
    const int qrow = q0 + w * 16 + cid;

    const int nkt = (qt >> 1) + 1;   // 128-key tiles
    PREFETCH(0);

    for (int kt = 0; kt < nkt; ++kt) {
        __syncthreads();            // prev-iter frag reads done; LDS writable
        *(uint4*)&Ks[w * 32 + 0  + srow8][ksw] = kr0;
        *(uint4*)&Ks[w * 32 + 8  + srow8][ksw] = kr1;
        *(uint4*)&Ks[w * 32 + 16 + srow8][ksw] = kr2;
        *(uint4*)&Ks[w * 32 + 24 + srow8][ksw] = kr3;
        *(uint4*)&Vs[w * 16 + 0  + vr0][spE] = vq0;
        *(uint4*)&Vs[w * 16 + 4  + vr0][spO] = vq1;
        *(uint4*)&Vs[w * 16 + 8  + vr0][spE] = vq2;
        *(uint4*)&Vs[w * 16 + 12 + vr0][spO] = vq3;
        __syncthreads();            // tiles visible
        if (kt + 1 < nkt) PREFETCH(kt + 1);   // in flight across compute

        // ---- S^T = K Q^T (swapped operands): lane holds
        //      S[key = 16t + 4*quad + i][q = cid]; exp2-prescaled. ----
        f4 sc[8];
#pragma unroll
        for (int t = 0; t < 8; ++t) {
            int r = t * 16 + cid;
            f4 a = {};
            a = __builtin_amdgcn_mfma_f32_16x16x32_bf16(KFRAG(r, quad), qfa, a, 0, 0, 0);
            a = __builtin_amdgcn_mfma_f32_16x16x32_bf16(KFRAG(r, quad + 4), qfb, a, 0, 0, 0);
            sc[t] = a;
        }

        // ---- causal mask (last tile only) ----
        if (kt == nkt - 1) {
#pragma unroll
            for (int t = 0; t < 8; ++t) {
#pragma unroll
                for (int i2 = 0; i2 < 4; ++i2) {
                    int key = kt * 128 + t * 16 + quad * 4 + i2;
                    if (key > qrow) sc[t][i2] = -1e30f;
                }
            }
        }

        // ---- exp2 (no l adds: l comes from the ones-MFMA below) ----
#pragma unroll
        for (int t = 0; t < 8; ++t)
#pragma unroll
            for (int i2 = 0; i2 < 4; ++i2)
                sc[t][i2] = exp2f(sc[t][i2]);

        // ---- pack P pairs, route via permlane32_swap + ds_swizzle ----
        unsigned int r_[8], r2_[8];
#pragma unroll
        for (int t = 0; t < 8; ++t) {
            r_[t]  = pkbf(sc[t][0], sc[t][1]);
            r2_[t] = pkbf(sc[t][2], sc[t][3]);
        }

        const bool qodd = (quad & 1) != 0;
#pragma unroll
        for (int f = 0; f < 4; ++f) {
            unsigned int xa = r_[2 * f], ya = r_[2 * f + 1];
            asm("v_permlane32_swap_b32 %0, %1" : "+v"(xa), "+v"(ya));
            unsigned int xas = __builtin_amdgcn_ds_swizzle((int)xa, 0x401f);
            unsigned int yas = __builtin_amdgcn_ds_swizzle((int)ya, 0x401f);
            unsigned int xb = r2_[2 * f], yb = r2_[2 * f + 1];
            asm("v_permlane32_swap_b32 %0, %1" : "+v"(xb), "+v"(yb));
            unsigned int xbs = __builtin_amdgcn_ds_swizzle((int)xb, 0x401f);
            unsigned int ybs = __builtin_amdgcn_ds_swizzle((int)yb, 0x401f);
            unsigned int u0 = qodd ? yas : xa;
            unsigned int u1 = qodd ? ybs : xb;
            unsigned int u2 = qodd ? ya : xas;
            unsigned int u3 = qodd ? yb : xbs;
            union { uint4 u; bf8 v; } pf;
            pf.u = (uint4){u0, u1, u2, u3};
#pragma unroll
            for (int t = 0; t < 4; ++t) {
                int r = t * 16 + cid;
                o[t] = __builtin_amdgcn_mfma_f32_16x16x32_bf16(
                    pf.v, VFRAG(r, 4 * f + quad), o[t], 0, 0, 0);
            }
            // l: sum of this P fragment's 32 keys (MFMA pipe, not VALU)
            o4 = __builtin_amdgcn_mfma_f32_16x16x32_bf16(pf.v, onesf.v, o4, 0, 0, 0);
        }
    }
#undef PREFETCH
#undef KFRAG
#undef VFRAG

    // ---- epilogue: inv directly from o4 (no cross-lane reduction) ----
#pragma unroll
    for (int i2 = 0; i2 < 4; ++i2) {
        const float invi = 1.0f / o4[i2];
        int rowg = q0 + w * 16 + quad * 4 + i2;
        size_t rbase = ((size_t)b * S_LEN + rowg) * U_DIM + h * DK;
#pragma unroll
        for (int t = 0; t < 4; ++t)
            O[rbase + t * 16 + cid] = f2bf(o[t][i2] * invi);
    }
}

// ---------------------------------------------------------------------------
// ws layout (bf16): xq|xk|xv (8MB ea) | wq|wk|wv|wo (2MB ea) |
//                   qg|kg|vt|ao (8MB ea)  = 64 MB total.
// ---------------------------------------------------------------------------
extern "C" void kernel_launch(void* const* d_in, const int* in_sizes, int n_in,
                              void* d_out, int out_size, void* d_ws, size_t ws_size,
                              hipStream_t stream)
{
    const float* query = (const float*)d_in[0];
    const float* key   = (const float*)d_in[1];
    const float* value = (const float*)d_in[2];
    const float* Wq = (const float*)d_in[4];
    const float* bq = (const float*)d_in[5];
    const float* Wk = (const float*)d_in[6];
    const float* bk = (const float*)d_in[7];
    const float* Wv = (const float*)d_in[8];
    const float* bv = (const float*)d_in[9];
    const float* Wo = (const float*)d_in[10];
    const float* bo = (const float*)d_in[11];
    float* out = (float*)d_out;

    const size_t ACT = (size_t)M_TOT * U_DIM;
    const size_t WT  = (size_t)U_DIM * U_DIM;

    unsigned short* xq  = (unsigned short*)d_ws;
    unsigned short* xk  = xq + ACT;
    unsigned short* xv  = xk + ACT;
    unsigned short* wqb = xv + ACT;
    unsigned short* wkb = wqb + WT;
    unsigned short* wvb = wkb + WT;
    unsigned short* wob = wvb + WT;
    unsigned short* qg  = wob + WT;
    unsigned short* kg  = qg + ACT;
    unsigned short* vt  = kg + ACT;
    unsigned short* ao  = vt + ACT;

    CvtArgs ca;
    ca.src[0] = query; ca.dst[0] = xq;  ca.n[0] = (int)ACT;
    ca.src[1] = key;   ca.dst[1] = xk;  ca.n[1] = (int)ACT;
    ca.src[2] = value; ca.dst[2] = xv;  ca.n[2] = (int)ACT;
    ca.src[3] = Wq;    ca.dst[3] = wqb; ca.n[3] = (int)WT;
    ca.src[4] = Wk;    ca.dst[4] = wkb; ca.n[4] = (int)WT;
    ca.src[5] = Wv;    ca.dst[5] = wvb; ca.n[5] = (int)WT;
    ca.src[6] = Wo;    ca.dst[6] = wob; ca.n[6] = (int)WT;
    convert_bf16<<<dim3(ACT / (256 * 8), 7), 256, 0, stream>>>(ca);

    // Q scale folds softmax's 1/sqrt(DK) AND log2(e) (attn uses exp2).
    QkvArgs ga;
    ga.A[0] = xq; ga.W[0] = wqb; ga.bias[0] = bq; ga.C[0] = qg;
    ga.scale[0] = 0.125f * 1.44269504088896340736f;
    ga.A[1] = xk; ga.W[1] = wkb; ga.bias[1] = bk; ga.C[1] = kg; ga.scale[1] = 1.0f;
    ga.A[2] = xv; ga.W[2] = wvb; ga.bias[2] = bv; ga.C[2] = vt; ga.scale[2] = 1.0f;
    gemm_qkv<<<dim3(U_DIM / 128, M_TOT / 128, 3), 256, 0, stream>>>(ga);

    attn_mfma<<<dim3(S_LEN / 64, H_NUM, B_NUM), 256, 0, stream>>>(qg, kg, vt, ao);

    gemm_obf<<<dim3(U_DIM / 128, M_TOT / 128), 256, 0, stream>>>(ao, wob, bo, out);
}